// Round 4
// baseline (4127.096 us; speedup 1.0000x reference)
//
#include <hip/hip_runtime.h>
#include <math.h>

#define E_N 200000
#define T_N 1000000
#define EPB 8   // edges per block in the triplet kernel

// silu with fp64 sigmoid
__device__ __forceinline__ double silu_d(double v) {
    return v / (1.0 + exp(-v));
}

// ---------------------------------------------------------------------------
// 64-row LDS tile @ W[128][128] (row-major l,c), fp64 accumulation
// thread t: rowgroup rg=t>>5 (8 rows), cols c0=(t&31)*4
// ---------------------------------------------------------------------------
__device__ __forceinline__ void gemm_tile_64x128_d(const float* __restrict__ A_lds,
                                                   const float* __restrict__ Wg,
                                                   double acc[8][4])
{
    const int t = threadIdx.x;
    const int rg = t >> 5;
    const int c0 = (t & 31) * 4;
    const float* arow = A_lds + rg * 8 * 128;
#pragma unroll 2
    for (int l0 = 0; l0 < 128; l0 += 4) {
        alignas(16) float w[4][4];
#pragma unroll
        for (int dl = 0; dl < 4; ++dl)
            *(float4*)w[dl] = *(const float4*)(Wg + (size_t)(l0 + dl) * 128 + c0);
        alignas(16) float a[8][4];
#pragma unroll
        for (int rr = 0; rr < 8; ++rr)
            *(float4*)a[rr] = *(const float4*)(arow + rr * 128 + l0);
#pragma unroll
        for (int rr = 0; rr < 8; ++rr)
#pragma unroll
            for (int dl = 0; dl < 4; ++dl)
#pragma unroll
                for (int cc = 0; cc < 4; ++cc)
                    acc[rr][cc] = fma((double)a[rr][dl], (double)w[dl][cc], acc[rr][cc]);
    }
}

__device__ __forceinline__ void load_tile_64x128(const float* __restrict__ g, float* lds, int r0)
{
    const int t = threadIdx.x;
    const float4* src = (const float4*)(g + (size_t)r0 * 128);
    float4* dst = (float4*)lds;
#pragma unroll
    for (int k = 0; k < 8; ++k) dst[t + 256 * k] = src[t + 256 * k];
}

// ---------------------------------------------------------------------------
// x_kj = silu(x @ kjw + kjb) * (rbf @ lrw)
// ---------------------------------------------------------------------------
__global__ __launch_bounds__(256) void k_edge(const float* __restrict__ x,
                                              const float* __restrict__ rbf,
                                              const float* __restrict__ lrw,
                                              const float* __restrict__ kjw,
                                              const float* __restrict__ kjb,
                                              float* __restrict__ xkj)
{
    __shared__ float A[64 * 128];
    __shared__ float RB[64 * 6];
    const int r0 = blockIdx.x * 64;
    load_tile_64x128(x, A, r0);
    const int t = threadIdx.x;
    // BUGFIX (round 4): 384 entries with 256 threads requires a strided loop.
    // Previous `if (t < 384)` left RB[256..383] uninitialized -> rows 42..63
    // of every tile got garbage rbf_h. This was the structural absmax~7 error.
    for (int k = t; k < 384; k += 256) RB[k] = rbf[(size_t)r0 * 6 + k];
    __syncthreads();

    double acc[8][4] = {};
    gemm_tile_64x128_d(A, kjw, acc);

    const int rg = t >> 5, c0 = (t & 31) * 4;
    alignas(16) float b[4];  *(float4*)b = *(const float4*)(kjb + c0);
    alignas(16) float lw[6][4];
#pragma unroll
    for (int k = 0; k < 6; ++k) *(float4*)lw[k] = *(const float4*)(lrw + k * 128 + c0);

#pragma unroll
    for (int rr = 0; rr < 8; ++rr) {
        const int r = rg * 8 + rr;
        double rh[4] = {0.0, 0.0, 0.0, 0.0};
#pragma unroll
        for (int k = 0; k < 6; ++k) {
            double rv = (double)RB[r * 6 + k];
#pragma unroll
            for (int cc = 0; cc < 4; ++cc) rh[cc] = fma(rv, (double)lw[k][cc], rh[cc]);
        }
        alignas(16) float o[4];
#pragma unroll
        for (int cc = 0; cc < 4; ++cc)
            o[cc] = (float)(silu_d(acc[rr][cc] + (double)b[cc]) * rh[cc]);
        *(float4*)(xkj + (size_t)(r0 + r) * 128 + c0) = *(float4*)o;
    }
}

// ---------------------------------------------------------------------------
// h0 = silu(x @ jiw + jib) + agg_d   (agg in fp64)
// ---------------------------------------------------------------------------
__global__ __launch_bounds__(256) void k_h0(const float* __restrict__ x,
                                            const float* __restrict__ Wg,
                                            const float* __restrict__ bg,
                                            const double* __restrict__ aggd,
                                            float* __restrict__ out)
{
    __shared__ float A[64 * 128];
    const int r0 = blockIdx.x * 64;
    load_tile_64x128(x, A, r0);
    __syncthreads();

    double acc[8][4] = {};
    gemm_tile_64x128_d(A, Wg, acc);

    const int t = threadIdx.x, rg = t >> 5, c0 = (t & 31) * 4;
    alignas(16) float b[4];  *(float4*)b = *(const float4*)(bg + c0);
#pragma unroll
    for (int rr = 0; rr < 8; ++rr) {
        const int r = r0 + rg * 8 + rr;
        alignas(16) float o[4];
#pragma unroll
        for (int cc = 0; cc < 4; ++cc) {
            double ad = aggd[(size_t)r * 128 + c0 + cc];
            o[cc] = (float)(silu_d(acc[rr][cc] + (double)b[cc]) + ad);
        }
        *(float4*)(out + (size_t)r * 128 + c0) = *(float4*)o;
    }
}

// ---------------------------------------------------------------------------
// out = silu(hin @ W + b) + add   (fp32 add-source; used for h2)
// ---------------------------------------------------------------------------
__global__ __launch_bounds__(256) void k_gemm_silu_add(const float* __restrict__ hin,
                                                       const float* __restrict__ Wg,
                                                       const float* __restrict__ bg,
                                                       const float* __restrict__ add,
                                                       float* __restrict__ out)
{
    __shared__ float A[64 * 128];
    const int r0 = blockIdx.x * 64;
    load_tile_64x128(hin, A, r0);
    __syncthreads();

    double acc[8][4] = {};
    gemm_tile_64x128_d(A, Wg, acc);

    const int t = threadIdx.x, rg = t >> 5, c0 = (t & 31) * 4;
    alignas(16) float b[4];  *(float4*)b = *(const float4*)(bg + c0);
#pragma unroll
    for (int rr = 0; rr < 8; ++rr) {
        const int r = r0 + rg * 8 + rr;
        alignas(16) float ad[4]; *(float4*)ad = *(const float4*)(add + (size_t)r * 128 + c0);
        alignas(16) float o[4];
#pragma unroll
        for (int cc = 0; cc < 4; ++cc)
            o[cc] = (float)(silu_d(acc[rr][cc] + (double)b[cc]) + (double)ad[cc]);
        *(float4*)(out + (size_t)r * 128 + c0) = *(float4*)o;
    }
}

// ---------------------------------------------------------------------------
// out = hin + silu(silu(hin@w1+b1)@w2+b2)
// ---------------------------------------------------------------------------
__global__ __launch_bounds__(256) void k_resblock(const float* __restrict__ hin,
                                                  const float* __restrict__ w1,
                                                  const float* __restrict__ b1,
                                                  const float* __restrict__ w2,
                                                  const float* __restrict__ b2,
                                                  float* __restrict__ out)
{
    __shared__ float A[64 * 128];
    const int r0 = blockIdx.x * 64;
    load_tile_64x128(hin, A, r0);
    __syncthreads();

    double acc[8][4] = {};
    gemm_tile_64x128_d(A, w1, acc);

    const int t = threadIdx.x, rg = t >> 5, c0 = (t & 31) * 4;
    alignas(16) float bb1[4]; *(float4*)bb1 = *(const float4*)(b1 + c0);
    __syncthreads();   // everyone done reading A
#pragma unroll
    for (int rr = 0; rr < 8; ++rr) {
        alignas(16) float o[4];
#pragma unroll
        for (int cc = 0; cc < 4; ++cc)
            o[cc] = (float)silu_d(acc[rr][cc] + (double)bb1[cc]);
        *(float4*)(A + (rg * 8 + rr) * 128 + c0) = *(float4*)o;
    }
    __syncthreads();

    double acc2[8][4] = {};
    gemm_tile_64x128_d(A, w2, acc2);
    alignas(16) float bb2[4]; *(float4*)bb2 = *(const float4*)(b2 + c0);
#pragma unroll
    for (int rr = 0; rr < 8; ++rr) {
        const int r = r0 + rg * 8 + rr;
        alignas(16) float hv[4]; *(float4*)hv = *(const float4*)(hin + (size_t)r * 128 + c0);
        alignas(16) float o[4];
#pragma unroll
        for (int cc = 0; cc < 4; ++cc)
            o[cc] = (float)((double)hv[cc] + silu_d(acc2[rr][cc] + (double)bb2[cc]));
        *(float4*)(out + (size_t)r * 128 + c0) = *(float4*)o;
    }
}

// ---------------------------------------------------------------------------
// Wt2[l][j*128+i] = W[i][j][l]
// ---------------------------------------------------------------------------
__global__ __launch_bounds__(256) void k_wt(const float* __restrict__ Wg, float* __restrict__ Wt2)
{
    const int o = blockIdx.x * 256 + threadIdx.x;   // 131072 total
    const int l = o >> 10, rest = o & 1023;
    const int j = rest >> 7, i = rest & 127;
    Wt2[o] = Wg[((size_t)(i * 8 + j)) * 128 + l];
}

// ---------------------------------------------------------------------------
// sbf_h[w] = sbf[w] @ lsw    ([T,42]@[42,8]), fp64 accum
// ---------------------------------------------------------------------------
__global__ __launch_bounds__(256) void k_sbfh(const float* __restrict__ sbf,
                                              const float* __restrict__ lsw,
                                              float* __restrict__ sbfh)
{
    __shared__ float S[256 * 42];
    __shared__ float Wl[42 * 8];
    const int r0 = blockIdx.x * 256;
    const int t = threadIdx.x;
    const int n = (T_N - r0 < 256) ? (T_N - r0) : 256;
    const int total = n * 42;
    for (int k = t; k < total; k += 256) S[k] = sbf[(size_t)r0 * 42 + k];
    for (int k = t; k < 336; k += 256) Wl[k] = lsw[k];
    __syncthreads();
    if (t < n) {
        double a[8] = {};
        const float* row = S + t * 42;
#pragma unroll
        for (int k = 0; k < 42; ++k) {
            double rv = (double)row[k];
#pragma unroll
            for (int j = 0; j < 8; ++j) a[j] = fma(rv, (double)Wl[k * 8 + j], a[j]);
        }
        alignas(16) float o[8];
#pragma unroll
        for (int j = 0; j < 8; ++j) o[j] = (float)a[j];
        *(float4*)(sbfh + (size_t)(r0 + t) * 8)     = *(float4*)o;
        *(float4*)(sbfh + (size_t)(r0 + t) * 8 + 4) = *(float4*)(o + 4);
    }
}

// ---------------------------------------------------------------------------
// counting-sort of triplets by idx_kj
// ---------------------------------------------------------------------------
__global__ __launch_bounds__(256) void k_hist(const int* __restrict__ idx_kj, int* __restrict__ counts)
{
    const int w = blockIdx.x * 256 + threadIdx.x;
    if (w < T_N) atomicAdd(counts + idx_kj[w], 1);
}

__global__ __launch_bounds__(1024) void k_scan(const int* __restrict__ counts,
                                               int* __restrict__ offsets,
                                               int* __restrict__ cursor)
{
    __shared__ int p[1024];
    const int t = threadIdx.x;
    const int lo = t * 196;
    const int hi = (lo + 196 < E_N) ? lo + 196 : E_N;
    int s = 0;
    for (int i = lo; i < hi; ++i) s += counts[i];
    p[t] = s;
    __syncthreads();
    for (int off = 1; off < 1024; off <<= 1) {
        int v = p[t];
        int add = (t >= off) ? p[t - off] : 0;
        __syncthreads();
        p[t] = v + add;
        __syncthreads();
    }
    int run = (t == 0) ? 0 : p[t - 1];
    for (int i = lo; i < hi; ++i) {
        offsets[i] = run;
        cursor[i]  = run;
        run += counts[i];
    }
    if (t == 1023) offsets[E_N] = p[1023];
}

__global__ __launch_bounds__(256) void k_scatter(const int* __restrict__ idx_kj,
                                                 int* __restrict__ cursor,
                                                 int* __restrict__ sorted_w)
{
    const int w = blockIdx.x * 256 + threadIdx.x;
    if (w < T_N) {
        int p = atomicAdd(cursor + idx_kj[w], 1);
        sorted_w[p] = w;
    }
}

// ---------------------------------------------------------------------------
// Fused z + triplet contraction + scatter-add (fp64 accum + fp64 atomics).
// ---------------------------------------------------------------------------
__global__ __launch_bounds__(256) void k_triplet(const float* __restrict__ xkj,
                                                 const float* __restrict__ Wt2,
                                                 const float* __restrict__ sbfh,
                                                 const int* __restrict__ offsets,
                                                 const int* __restrict__ sorted_w,
                                                 const int* __restrict__ idx_kj,
                                                 const int* __restrict__ idx_ji,
                                                 double* __restrict__ aggd)
{
    __shared__ float z[EPB * 1024];
    const int e0 = blockIdx.x * EPB;
    const int t = threadIdx.x;
    const int c0 = t * 4;

    double acc[EPB][4] = {};
    const float* xk = xkj + (size_t)e0 * 128;
#pragma unroll 2
    for (int l0 = 0; l0 < 128; l0 += 4) {
        alignas(16) float w[4][4];
#pragma unroll
        for (int dl = 0; dl < 4; ++dl)
            *(float4*)w[dl] = *(const float4*)(Wt2 + (size_t)(l0 + dl) * 1024 + c0);
#pragma unroll
        for (int e = 0; e < EPB; ++e) {
            alignas(16) float a[4];
            *(float4*)a = *(const float4*)(xk + e * 128 + l0);
#pragma unroll
            for (int dl = 0; dl < 4; ++dl)
#pragma unroll
                for (int cc = 0; cc < 4; ++cc)
                    acc[e][cc] = fma((double)a[dl], (double)w[dl][cc], acc[e][cc]);
        }
    }
#pragma unroll
    for (int e = 0; e < EPB; ++e) {
        alignas(16) float o[4];
#pragma unroll
        for (int cc = 0; cc < 4; ++cc) o[cc] = (float)acc[e][cc];
        *(float4*)(&z[e * 1024 + c0]) = *(float4*)o;
    }
    __syncthreads();

    const int ts = offsets[e0];
    const int te = offsets[e0 + EPB];
    const int slot = t >> 7;
    const int i = t & 127;
    for (int base = ts; base < te; base += 2) {
        const int wi = base + slot;
        if (wi < te) {
            const int w_ = sorted_w[wi];
            const int kj = idx_kj[w_];
            const int ji = idx_ji[w_];
            const int le = kj - e0;
            alignas(16) float sh[8];
            *(float4*)sh       = *(const float4*)(sbfh + (size_t)w_ * 8);
            *(float4*)(sh + 4) = *(const float4*)(sbfh + (size_t)w_ * 8 + 4);
            double m = 0.0;
#pragma unroll
            for (int j = 0; j < 8; ++j)
                m = fma((double)sh[j], (double)z[le * 1024 + j * 128 + i], m);
            atomicAdd(aggd + (size_t)ji * 128 + i, m);
        }
    }
}

// ---------------------------------------------------------------------------
extern "C" void kernel_launch(void* const* d_in, const int* in_sizes, int n_in,
                              void* d_out, int out_size, void* d_ws, size_t ws_size,
                              hipStream_t stream)
{
    const float* x    = (const float*)d_in[0];
    const float* rbf  = (const float*)d_in[1];
    const float* sbf  = (const float*)d_in[2];
    const int*   ikj  = (const int*)d_in[3];
    const int*   iji  = (const int*)d_in[4];
    const float* lrw  = (const float*)d_in[5];
    const float* lsw  = (const float*)d_in[6];
    const float* kjw  = (const float*)d_in[7];
    const float* kjb  = (const float*)d_in[8];
    const float* jiw  = (const float*)d_in[9];
    const float* jib  = (const float*)d_in[10];
    const float* Wg   = (const float*)d_in[11];
    const float* bw1  = (const float*)d_in[12];
    const float* bb1  = (const float*)d_in[13];
    const float* bw2  = (const float*)d_in[14];
    const float* bb2  = (const float*)d_in[15];
    const float* lw   = (const float*)d_in[16];
    const float* lb   = (const float*)d_in[17];
    const float* aw1  = (const float*)d_in[18];
    const float* ab1  = (const float*)d_in[19];
    const float* aw2  = (const float*)d_in[20];
    const float* ab2  = (const float*)d_in[21];

    float* out = (float*)d_out;

    // workspace layout (~346 MB)
    float*  bufA  = (float*)d_ws;                      // E*128 f32: xkj -> h0 -> h2
    double* aggd  = (double*)(bufA + (size_t)E_N * 128); // E*128 f64 agg; reused as f32 bufC
    float*  bufC  = (float*)aggd;                      // h1 / h3 (after agg is dead)
    float*  sbfh  = (float*)(aggd + (size_t)E_N * 128);// T*8 f32
    float*  Wt2   = sbfh + (size_t)T_N * 8;            // 128*1024 f32
    int*    counts= (int*)(Wt2 + 131072);              // E
    int*    offs  = counts + E_N;                      // E+1
    int*    cursor= offs + E_N + 1;                    // E
    int*    sortw = cursor + E_N;                      // T

    hipMemsetAsync(counts, 0, (size_t)E_N * 4, stream);
    hipMemsetAsync(aggd, 0, (size_t)E_N * 128 * 8, stream);

    k_wt<<<512, 256, 0, stream>>>(Wg, Wt2);
    k_sbfh<<<(T_N + 255) / 256, 256, 0, stream>>>(sbf, lsw, sbfh);
    k_edge<<<E_N / 64, 256, 0, stream>>>(x, rbf, lrw, kjw, kjb, bufA);
    k_hist<<<(T_N + 255) / 256, 256, 0, stream>>>(ikj, counts);
    k_scan<<<1, 1024, 0, stream>>>(counts, offs, cursor);
    k_scatter<<<(T_N + 255) / 256, 256, 0, stream>>>(ikj, cursor, sortw);
    k_triplet<<<E_N / EPB, 256, 0, stream>>>(bufA, Wt2, sbfh, offs, sortw, ikj, iji, aggd);

    // h0 = silu(x@jiw+jib) + agg   -> bufA (xkj dead)
    k_h0<<<E_N / 64, 256, 0, stream>>>(x, jiw, jib, aggd, bufA);
    // h1 = h0 + silu(silu(h0@bw1+bb1)@bw2+bb2) -> bufC (agg dead)
    k_resblock<<<E_N / 64, 256, 0, stream>>>(bufA, bw1, bb1, bw2, bb2, bufC);
    // h2 = silu(h1@lw+lb) + x -> bufA
    k_gemm_silu_add<<<E_N / 64, 256, 0, stream>>>(bufC, lw, lb, x, bufA);
    // h3 = resblock(h2, aw[0]) -> bufC
    k_resblock<<<E_N / 64, 256, 0, stream>>>(bufA, aw1, ab1, aw2, ab2, bufC);
    // h4 = resblock(h3, aw[1]) -> d_out
    k_resblock<<<E_N / 64, 256, 0, stream>>>(bufC, aw1 + 128 * 128, ab1 + 128,
                                             aw2 + 128 * 128, ab2 + 128, out);
}